// Round 1
// baseline (24.110 us; speedup 1.0000x reference)
//
#include <hip/hip_runtime.h>
#include <hip/hip_bf16.h>

#define TCTX 500
#define DFEAT 8192
#define TD 64      // d-columns per block
#define TT 128     // t-rows per block

__global__ __launch_bounds__(256) void MegaMerge_77283641524594_kernel(
    const float* __restrict__ h,
    const float* __restrict__ c2q,
    const float* __restrict__ q2c,
    float* __restrict__ out)
{
    // LDS holds the h tile TRANSPOSED: hs[d_local][t_local], +1 pad kills
    // power-of-2 stride bank conflicts on the store side.
    __shared__ float hs[TD][TT + 1];

    const int tid = threadIdx.x;
    const int d0  = blockIdx.x * TD;   // feature-column base
    const int t0  = blockIdx.y * TT;   // context-row base

    // ---- Load phase: coalesced float4 reads of h[t, d0:d0+64] ----
    // 256 threads = 16 d-chunks (float4) x 16 t-rows; 8 passes cover TT=128.
    {
        const int dc = (tid & 15) * 4;  // d offset within tile (0,4,...,60)
        const int tr = tid >> 4;        // t row within pass (0..15)
        #pragma unroll
        for (int it = 0; it < TT; it += 16) {
            const int t = t0 + tr + it;
            if (t < TCTX) {
                const float4 v = *reinterpret_cast<const float4*>(
                    &h[(size_t)t * DFEAT + d0 + dc]);
                hs[dc + 0][tr + it] = v.x;
                hs[dc + 1][tr + it] = v.y;
                hs[dc + 2][tr + it] = v.z;
                hs[dc + 3][tr + it] = v.w;
            }
        }
    }
    __syncthreads();

    // ---- Compute/store phase: t-contiguous lanes -> coalesced global I/O ----
    // 256 threads = 128 t-lanes x 2 d-rows; loop covers 64 d-rows.
    const int tl = tid & (TT - 1);
    const int t  = t0 + tl;
    if (t < TCTX) {
        #pragma unroll 4
        for (int dl = (tid >> 7); dl < TD; dl += 2) {
            const int j = d0 + dl;
            const float hv = hs[dl][tl];                 // conflict-free row read
            const float c  = c2q[(size_t)j * TCTX + t];  // coalesced
            const float q  = q2c[(size_t)j * TCTX + t];  // coalesced
            out[(size_t)j               * TCTX + t] = hv;      // section 0: H^T
            out[(size_t)(DFEAT + j)     * TCTX + t] = c;       // section 1: c2q copy
            out[(size_t)(2 * DFEAT + j) * TCTX + t] = hv * c;  // section 2: H*C
            out[(size_t)(3 * DFEAT + j) * TCTX + t] = hv * q;  // section 3: H*Q
        }
    }
}

extern "C" void kernel_launch(void* const* d_in, const int* in_sizes, int n_in,
                              void* d_out, int out_size, void* d_ws, size_t ws_size,
                              hipStream_t stream) {
    const float* h   = (const float*)d_in[0];
    const float* c2q = (const float*)d_in[1];
    const float* q2c = (const float*)d_in[2];
    float* out = (float*)d_out;

    dim3 grid(DFEAT / TD, (TCTX + TT - 1) / TT);  // 128 x 4
    dim3 block(256);
    MegaMerge_77283641524594_kernel<<<grid, block, 0, stream>>>(h, c2q, q2c, out);
}

// Round 2
// 23.710 us; speedup vs baseline: 1.0168x; 1.0168x over previous
//
#include <hip/hip_runtime.h>
#include <hip/hip_bf16.h>

#define TCTX 500
#define DFEAT 8192
#define TD 32                 // d-columns per block
#define TT 128                // t-values per block (32 float4 groups)
#define LDS_STRIDE (TT + 4)   // floats; 16B-aligned rows, breaks pow-2 stride

__global__ __launch_bounds__(256) void MegaMerge_77283641524594_kernel(
    const float* __restrict__ h,
    const float* __restrict__ c2q,
    const float* __restrict__ q2c,
    float* __restrict__ out)
{
    // h tile staged TRANSPOSED: hs[d_local][t_local]
    __shared__ float hs[TD * LDS_STRIDE];

    const int tid = threadIdx.x;
    const int d0  = blockIdx.x * TD;   // feature-column base
    const int t0  = blockIdx.y * TT;   // context base

    // ---- Load phase: coalesced float4 reads of h[t, d0:d0+32] ----
    // 256 threads = 8 d-chunks (float4) x 32 t-rows; 4 passes cover TT=128.
    {
        const int dc = (tid & 7) * 4;   // d offset in tile: 0,4,...,28
        const int tr = tid >> 3;        // t row in pass: 0..31
        #pragma unroll
        for (int it = 0; it < TT; it += 32) {
            const int t = t0 + tr + it;
            if (t < TCTX) {
                const float4 v = *reinterpret_cast<const float4*>(
                    &h[(size_t)t * DFEAT + d0 + dc]);
                const int tl = tr + it;
                hs[(dc + 0) * LDS_STRIDE + tl] = v.x;
                hs[(dc + 1) * LDS_STRIDE + tl] = v.y;
                hs[(dc + 2) * LDS_STRIDE + tl] = v.z;
                hs[(dc + 3) * LDS_STRIDE + tl] = v.w;
            }
        }
    }
    __syncthreads();

    // ---- Store phase: float4 along t, fully coalesced 1KB/wave I/O ----
    // 256 threads = 32 t4-lanes x 8 d-rows; 4 iterations cover TD=32.
    const int t4 = tid & 31;
    const int t  = t0 + t4 * 4;
    if (t < TCTX) {   // t multiple of 4 and 500%4==0 -> guards full float4
        #pragma unroll
        for (int dl = (tid >> 5); dl < TD; dl += 8) {
            const int j = d0 + dl;
            const float4 hv = *reinterpret_cast<const float4*>(
                &hs[dl * LDS_STRIDE + t4 * 4]);
            const float4 c = *reinterpret_cast<const float4*>(
                &c2q[(size_t)j * TCTX + t]);
            const float4 q = *reinterpret_cast<const float4*>(
                &q2c[(size_t)j * TCTX + t]);
            const float4 hc = make_float4(hv.x * c.x, hv.y * c.y,
                                          hv.z * c.z, hv.w * c.w);
            const float4 hq = make_float4(hv.x * q.x, hv.y * q.y,
                                          hv.z * q.z, hv.w * q.w);
            *reinterpret_cast<float4*>(&out[(size_t)j               * TCTX + t]) = hv;
            *reinterpret_cast<float4*>(&out[(size_t)(DFEAT + j)     * TCTX + t]) = c;
            *reinterpret_cast<float4*>(&out[(size_t)(2 * DFEAT + j) * TCTX + t]) = hc;
            *reinterpret_cast<float4*>(&out[(size_t)(3 * DFEAT + j) * TCTX + t]) = hq;
        }
    }
}

extern "C" void kernel_launch(void* const* d_in, const int* in_sizes, int n_in,
                              void* d_out, int out_size, void* d_ws, size_t ws_size,
                              hipStream_t stream) {
    const float* h   = (const float*)d_in[0];
    const float* c2q = (const float*)d_in[1];
    const float* q2c = (const float*)d_in[2];
    float* out = (float*)d_out;

    dim3 grid(DFEAT / TD, (TCTX + TT - 1) / TT);  // 256 x 4 = 1024 blocks
    dim3 block(256);
    MegaMerge_77283641524594_kernel<<<grid, block, 0, stream>>>(h, c2q, q2c, out);
}